// Round 7
// baseline (105.519 us; speedup 1.0000x reference)
//
#include <hip/hip_runtime.h>
#include <math.h>

#define B_ROWS 4096
#define LBL 100
#define NCT 32   // full 32x32 grid of 128x128 C tiles

typedef __attribute__((ext_vector_type(8))) short bf16x8;
typedef __attribute__((ext_vector_type(4))) float f32x4;

__device__ __forceinline__ unsigned f2bf(float x) {
  union { float f; unsigned u; } a; a.f = x;
  unsigned r = a.u + 0x7fffu + ((a.u >> 16) & 1u);  // RNE
  return r >> 16;
}
__device__ __forceinline__ float bf2f(unsigned h) {
  return __uint_as_float(h << 16);
}

// One wave per row: 128-bit label mask + row sum.
__global__ void label_kernel(const float* __restrict__ labels,
                             uint4* __restrict__ Lb,
                             int* __restrict__ rsv) {
  int w = (int)((blockIdx.x * blockDim.x + threadIdx.x) >> 6);
  int lane = threadIdx.x & 63;
  float x0 = labels[(size_t)w * LBL + lane];
  float x1 = (lane < LBL - 64) ? labels[(size_t)w * LBL + 64 + lane] : 0.0f;
  unsigned long long m0 = __ballot(x0 != 0.0f);
  unsigned long long m1 = __ballot(x1 != 0.0f);
  if (lane == 0) {
    Lb[w] = make_uint4((unsigned)m0, (unsigned)(m0 >> 32),
                       (unsigned)m1, (unsigned)(m1 >> 32));
    rsv[w] = __popcll(m0) + __popcll(m1);
  }
}

// One 128x128 C tile per block, FULL 32x32 grid (row-side epilogue only).
// Stages fp32 feat directly (f2bf in VGPR -> XOR-swizzled LDS), computes the
// per-row exp reference in-block (bit-identical across blocks: same inputs,
// same op order), MFMA raw dots, fast-path epilogue. logits_max cancels in
// -log(p/(p+n)); terms below ref-6.3 raw (=90 logits under the diag logit)
// underflow to exactly 0 in the reference's fp32 sums too.
__launch_bounds__(256, 2)
__global__ void main_kernel(const float* __restrict__ feat,
                            const uint4* __restrict__ Lb,
                            const int* __restrict__ rsv,
                            float2* __restrict__ part) {
  __shared__ uint4 As[2048];   // 32 KB bf16 row tile, XOR-swizzled chunks
  __shared__ uint4 Bs[2048];   // 32 KB bf16 col tile
  __shared__ uint4 rLbS[128], cLbS[128];
  __shared__ int rRsS[128], cRsS[128];
  __shared__ float sS[128];    // row exp references

  const int bx = blockIdx.x;   // row tile
  const int by = blockIdx.y;   // col tile
  const int tid = threadIdx.x;
  const int lane = tid & 63;
  const int l15 = lane & 15;
  const int quad = lane >> 4;
  const int wave = tid >> 6;
  const int wi = (wave & 1) * 64;   // wave row offset in 128
  const int wj = (wave >> 1) * 64;  // wave col offset in 128
  const int rowBase = bx * 128;
  const int colBase = by * 128;
  const float invT = 1.0f / 0.07f;

  // stage both tiles: coalesced fp32 reads (16 threads sweep one row), f2bf,
  // swizzled ds_write (chunk (r,kc) -> kc*128+(r^kc); <=2-way banks = free)
  #pragma unroll
  for (int it = 0; it < 8; ++it) {
    int flat = it * 256 + tid;
    int r = flat >> 4, kc = flat & 15;
    const float* pa = feat + (size_t)(rowBase + r) * 256 + kc * 8;  // view0
    float4 a0 = *(const float4*)pa;
    float4 a1 = *(const float4*)(pa + 4);
    uint4 av;
    av.x = f2bf(a0.x) | (f2bf(a0.y) << 16);
    av.y = f2bf(a0.z) | (f2bf(a0.w) << 16);
    av.z = f2bf(a1.x) | (f2bf(a1.y) << 16);
    av.w = f2bf(a1.z) | (f2bf(a1.w) << 16);
    As[kc * 128 + (r ^ kc)] = av;
    const float* pb = feat + (size_t)(colBase + r) * 256 + kc * 8;
    float4 b0 = *(const float4*)pb;
    float4 b1 = *(const float4*)(pb + 4);
    uint4 bv;
    bv.x = f2bf(b0.x) | (f2bf(b0.y) << 16);
    bv.y = f2bf(b0.z) | (f2bf(b0.w) << 16);
    bv.z = f2bf(b1.x) | (f2bf(b1.y) << 16);
    bv.w = f2bf(b1.z) | (f2bf(b1.w) << 16);
    Bs[kc * 128 + (r ^ kc)] = bv;
  }
  if (tid < 128) {
    cLbS[tid] = Lb[colBase + tid];
    cRsS[tid] = rsv[colBase + tid];
  } else {
    int t = tid - 128;
    rLbS[t] = Lb[rowBase + t];
    rRsS[t] = rsv[rowBase + t];
  }
  __syncthreads();

  // exp reference: ref = sum(bf16(f)^2) - 0.15 (lower bound on the raw diag
  // MFMA dot; reassoc err ~1e-3 << slack). Same op order in every block ->
  // bit-identical reference for a given global row.
  if (tid < 128) {
    float s = 0.f;
    #pragma unroll
    for (int kc = 0; kc < 16; ++kc) {
      uint4 c = As[kc * 128 + (tid ^ kc)];
      float v;
      v = bf2f(c.x & 0xffffu); s += v * v;
      v = bf2f(c.x >> 16);     s += v * v;
      v = bf2f(c.y & 0xffffu); s += v * v;
      v = bf2f(c.y >> 16);     s += v * v;
      v = bf2f(c.z & 0xffffu); s += v * v;
      v = bf2f(c.z >> 16);     s += v * v;
      v = bf2f(c.w & 0xffffu); s += v * v;
      v = bf2f(c.w >> 16);     s += v * v;
    }
    sS[tid] = s - 0.15f;
  }
  __syncthreads();

  float srow[16];
  #pragma unroll
  for (int ti = 0; ti < 4; ++ti)
    #pragma unroll
    for (int r = 0; r < 4; ++r)
      srow[ti * 4 + r] = sS[wi + ti * 16 + quad * 4 + r];

  const bf16x8* Asv = (const bf16x8*)As;
  const bf16x8* Bsv = (const bf16x8*)Bs;

  f32x4 acc[4][4];
  #pragma unroll
  for (int ti = 0; ti < 4; ++ti)
    #pragma unroll
    for (int tj = 0; tj < 4; ++tj)
      acc[ti][tj] = (f32x4){0.f, 0.f, 0.f, 0.f};

  #pragma unroll
  for (int ks = 0; ks < 4; ++ks) {
    const int kc = ks * 4 + quad;
    const int abase = kc * 128 + wi + (l15 ^ kc);
    const int bbase = kc * 128 + wj + (l15 ^ kc);
    bf16x8 af[4], bfr[4];
    #pragma unroll
    for (int t = 0; t < 4; ++t) {
      af[t] = Asv[abase + t * 16];
      bfr[t] = Bsv[bbase + t * 16];
    }
    #pragma unroll
    for (int ti = 0; ti < 4; ++ti)
      #pragma unroll
      for (int tj = 0; tj < 4; ++tj)
        acc[ti][tj] = __builtin_amdgcn_mfma_f32_16x16x32_bf16(
            af[ti], bfr[tj], acc[ti][tj], 0, 0, 0);
  }

  // epilogue: C[row][col], row=wi+ti*16+quad*4+r, col=wj+tj*16+l15 (raw dots)
  float p_s[16], n_s[16];
  #pragma unroll
  for (int i = 0; i < 16; ++i) { p_s[i] = 0.f; n_s[i] = 0.f; }
  #pragma unroll
  for (int ti = 0; ti < 4; ++ti)
    #pragma unroll
    for (int r = 0; r < 4; ++r) {
      int si = ti * 4 + r;
      float l0 = acc[ti][0][r], l1 = acc[ti][1][r];
      float l2 = acc[ti][2][r], l3 = acc[ti][3][r];
      float tm = fmaxf(fmaxf(l0, l1), fmaxf(l2, l3));
      if (tm > srow[si] - 6.3f) {  // survives exp vs diag reference (rare)
        int lrow = wi + ti * 16 + quad * 4 + r;
        uint4 la = rLbS[lrow];
        int ra = rRsS[lrow];
        float p = p_s[si], n = n_s[si];
        float lv[4] = {l0, l1, l2, l3};
        #pragma unroll
        for (int tj = 0; tj < 4; ++tj) {
          float e = __expf((lv[tj] - srow[si]) * invT);
          int lcol = wj + tj * 16 + l15;
          uint4 lb = cLbS[lcol];
          int inter = __popc(la.x & lb.x) + __popc(la.y & lb.y) +
                      __popc(la.z & lb.z) + __popc(la.w & lb.w);
          if (3 * inter > ra + cRsS[lcol]) p += e; else n += e;  // sim>=0.5 exact
        }
        p_s[si] = p;
        n_s[si] = n;
      }
    }

  // sum across the 16 lanes (same quad) sharing each row
  #pragma unroll
  for (int si = 0; si < 16; ++si) {
    float p = p_s[si], n = n_s[si];
    #pragma unroll
    for (int o = 8; o >= 1; o >>= 1) {
      p += __shfl_xor(p, o);
      n += __shfl_xor(n, o);
    }
    p_s[si] = p;
    n_s[si] = n;
  }

  // merge the two waves sharing each row (wj=0 / wj=64) via LDS, then store
  __syncthreads();
  float* mbuf = (float*)As;  // As dead; reuse
  if (wj == 64 && l15 == 0) {
    #pragma unroll
    for (int ti = 0; ti < 4; ++ti)
      #pragma unroll
      for (int r = 0; r < 4; ++r) {
        int row = wi + ti * 16 + quad * 4 + r;
        int si = ti * 4 + r;
        mbuf[row * 2 + 0] = p_s[si];
        mbuf[row * 2 + 1] = n_s[si];
      }
  }
  __syncthreads();
  if (wj == 0 && l15 == 0) {
    #pragma unroll
    for (int ti = 0; ti < 4; ++ti)
      #pragma unroll
      for (int r = 0; r < 4; ++r) {
        int row = wi + ti * 16 + quad * 4 + r;
        int si = ti * 4 + r;
        float p = p_s[si] + mbuf[row * 2 + 0];
        float n = n_s[si] + mbuf[row * 2 + 1];
        part[(size_t)by * B_ROWS + rowBase + row] = make_float2(p, n);
      }
  }
}

// single block: sum 32 chunks per row, per-row loss, block reduce, final div
__global__ void mergefin_kernel(const float2* __restrict__ part,
                                const int* __restrict__ rsv,
                                float* __restrict__ out) {
  __shared__ float red[8];
  int t = threadIdx.x;
  float per = 0.f, cnt = 0.f;
  #pragma unroll
  for (int i = 0; i < 16; ++i) {
    int row = i * 256 + t;
    float p = 0.f, n = 0.f;
    #pragma unroll
    for (int c = 0; c < NCT; ++c) {
      float2 v = part[(size_t)c * B_ROWS + row];
      p += v.x;
      n += v.y;
    }
    if (rsv[row] > 0) {  // exact: has_pos <=> row_sum > 0
      per += -logf(p / (p + n));
      cnt += 1.f;
    }
  }
  #pragma unroll
  for (int o = 32; o >= 1; o >>= 1) {
    per += __shfl_xor(per, o);
    cnt += __shfl_xor(cnt, o);
  }
  int wv = t >> 6;
  if ((t & 63) == 0) { red[wv * 2] = per; red[wv * 2 + 1] = cnt; }
  __syncthreads();
  if (t == 0) {
    float P = red[0] + red[2] + red[4] + red[6];
    float C = red[1] + red[3] + red[5] + red[7];
    out[0] = P / fmaxf(C, 1.0f);
  }
}

extern "C" void kernel_launch(void* const* d_in, const int* in_sizes, int n_in,
                              void* d_out, int out_size, void* d_ws, size_t ws_size,
                              hipStream_t stream) {
  const float* feat = (const float*)d_in[0];
  const float* labels = (const float*)d_in[1];
  float* out = (float*)d_out;
  char* ws = (char*)d_ws;
  // workspace (~1.1 MB):
  uint4* Lbm = (uint4*)(ws + 0);            // 64 KB label masks
  int* rsv = (int*)(ws + 65536);            // 16 KB row sums
  float2* part = (float2*)(ws + 81920);     // 1 MB partials (32 x 4096)

  hipLaunchKernelGGL(label_kernel, dim3(1024), dim3(256), 0, stream,
                     labels, Lbm, rsv);
  hipLaunchKernelGGL(main_kernel, dim3(NCT, NCT), dim3(256), 0, stream,
                     feat, Lbm, rsv, part);
  hipLaunchKernelGGL(mergefin_kernel, dim3(1), dim3(256), 0, stream,
                     part, rsv, out);
}

// Round 8
// 83.305 us; speedup vs baseline: 1.2666x; 1.2666x over previous
//
#include <hip/hip_runtime.h>
#include <math.h>

#define B_ROWS 4096
#define LBL 100
#define NCT 32     // 32x32 tile grid, upper triangle only
#define NTRI 528   // 32*33/2 blocks

typedef __attribute__((ext_vector_type(8))) short bf16x8;
typedef __attribute__((ext_vector_type(4))) float f32x4;

__device__ __forceinline__ unsigned f2bf(float x) {
  union { float f; unsigned u; } a; a.f = x;
  unsigned r = a.u + 0x7fffu + ((a.u >> 16) & 1u);  // RNE
  return r >> 16;
}

// async global->LDS DMA, 16B/lane; LDS dest = wave-uniform base + lane*16
__device__ __forceinline__ void lds_dma16(void* l, const void* g) {
  __builtin_amdgcn_global_load_lds(
      (const __attribute__((address_space(1))) void*)g,
      (__attribute__((address_space(3))) void*)l, 16, 0, 0);
}

// cf: bf16(view0), XOR-swizzled per 128-row tile: logical chunk (r,kc) of
// tile t lives at cf[t*2048 + kc*128 + (r^kc)] (uint4 = 8 bf16).
// One thread per chunk; reads coalesced (16 threads sweep one row).
__global__ void pack_kernel(const float* __restrict__ feat,
                            uint4* __restrict__ cf) {
  int g = blockIdx.x * 256 + threadIdx.x;  // chunk id, 65536 total
  int tile = g >> 11, rem = g & 2047;
  int r = rem >> 4, kc = rem & 15;
  const float* src = feat + ((size_t)(tile * 128 + r)) * 256 + kc * 8;  // view0
  float4 a = *(const float4*)src;
  float4 b = *(const float4*)(src + 4);
  uint4 ov;
  ov.x = f2bf(a.x) | (f2bf(a.y) << 16);
  ov.y = f2bf(a.z) | (f2bf(a.w) << 16);
  ov.z = f2bf(b.x) | (f2bf(b.y) << 16);
  ov.w = f2bf(b.z) | (f2bf(b.w) << 16);
  cf[(size_t)tile * 2048 + kc * 128 + (r ^ kc)] = ov;
}

// One wave per row: 128-bit label mask, row sum, seedRaw = sum(bf16(f)^2)-0.15
// (lower bound on the raw diag MFMA dot; reassoc err ~1e-3 << slack; single
// source -> trivially bit-identical across consumers). Block 0 zeroes accum.
__global__ void seedlabel_kernel(const float* __restrict__ feat,
                                 const float* __restrict__ labels,
                                 uint4* __restrict__ Lb,
                                 int* __restrict__ rsv,
                                 float* __restrict__ seedRaw,
                                 float* __restrict__ accum) {
  if (blockIdx.x == 0 && threadIdx.x < 2) accum[threadIdx.x] = 0.0f;
  int w = (int)((blockIdx.x * blockDim.x + threadIdx.x) >> 6);
  int lane = threadIdx.x & 63;
  const float2* src = (const float2*)(feat + (size_t)w * 256);  // view0 row
  float2 f = src[lane];
  float b0 = __uint_as_float(f2bf(f.x) << 16);
  float b1 = __uint_as_float(f2bf(f.y) << 16);
  float s = b0 * b0 + b1 * b1;
  #pragma unroll
  for (int o = 32; o >= 1; o >>= 1) s += __shfl_xor(s, o);
  float x0 = labels[(size_t)w * LBL + lane];
  float x1 = (lane < LBL - 64) ? labels[(size_t)w * LBL + 64 + lane] : 0.0f;
  unsigned long long m0 = __ballot(x0 != 0.0f);
  unsigned long long m1 = __ballot(x1 != 0.0f);
  if (lane == 0) {
    Lb[w] = make_uint4((unsigned)m0, (unsigned)(m0 >> 32),
                       (unsigned)m1, (unsigned)(m1 >> 32));
    rsv[w] = __popcll(m0) + __popcll(m1);
    seedRaw[w] = s - 0.15f;  // 0.15 raw = 2.1 logit slack
  }
}

// One upper-triangle 128x128 tile per block; bf16 tiles DMA-staged from cf
// (64 KB/block -> 34 MB total, the traffic that sets main's duration).
// MFMA raw dots; fast-path epilogue; row-side AND col-side partials
// (symmetry). logits_max cancels in -log(p/(p+n)); terms below ref-6.3 raw
// (=90 logits under the diag logit) underflow to 0 in the reference too.
__launch_bounds__(256, 2)
__global__ void main_kernel(const uint4* __restrict__ cf,
                            const uint4* __restrict__ Lb,
                            const int* __restrict__ rsv,
                            const float* __restrict__ seedRaw,
                            float2* __restrict__ part) {
  __shared__ uint4 As[2048];   // 32 KB pre-swizzled row tile
  __shared__ uint4 Bs[2048];   // 32 KB pre-swizzled col tile
  __shared__ uint4 rLbS[128], cLbS[128];
  __shared__ int rRsS[128], cRsS[128];
  __shared__ float sS[128], sB[128];  // row / col exp references

  // triangular decode: bid -> (bx, by), bx <= by
  int bid = blockIdx.x;
  int bx = 0, off = 0;
  while (bid >= off + (NCT - bx)) { off += NCT - bx; ++bx; }
  int by = bx + (bid - off);
  const bool diag = (bx == by);

  const int tid = threadIdx.x;
  const int lane = tid & 63;
  const int l15 = lane & 15;
  const int quad = lane >> 4;
  const int wave = tid >> 6;
  const int wi = (wave & 1) * 64;   // wave row offset in 128
  const int wj = (wave >> 1) * 64;  // wave col offset in 128
  const int rowBase = bx * 128;
  const int colBase = by * 128;
  const float invT = 1.0f / 0.07f;

  // issue ALL staging DMA up front (16 in flight/lane), then metadata
  #pragma unroll
  for (int it = 0; it < 8; ++it) {
    int flat = it * 256 + tid;
    lds_dma16(&As[flat], &cf[(size_t)bx * 2048 + flat]);
    lds_dma16(&Bs[flat], &cf[(size_t)by * 2048 + flat]);
  }
  if (tid < 128) {
    cLbS[tid] = Lb[colBase + tid];
    cRsS[tid] = rsv[colBase + tid];
    sB[tid] = seedRaw[colBase + tid];
  } else {
    int t = tid - 128;
    rLbS[t] = Lb[rowBase + t];
    rRsS[t] = rsv[rowBase + t];
    sS[t] = seedRaw[rowBase + t];
  }
  __syncthreads();  // drains DMA (vmcnt) + metadata (lgkmcnt)

  float srow[16], scol[4];
  #pragma unroll
  for (int ti = 0; ti < 4; ++ti)
    #pragma unroll
    for (int r = 0; r < 4; ++r)
      srow[ti * 4 + r] = sS[wi + ti * 16 + quad * 4 + r];
  #pragma unroll
  for (int tj = 0; tj < 4; ++tj) scol[tj] = sB[wj + tj * 16 + l15];

  const bf16x8* Asv = (const bf16x8*)As;
  const bf16x8* Bsv = (const bf16x8*)Bs;

  f32x4 acc[4][4];
  #pragma unroll
  for (int ti = 0; ti < 4; ++ti)
    #pragma unroll
    for (int tj = 0; tj < 4; ++tj)
      acc[ti][tj] = (f32x4){0.f, 0.f, 0.f, 0.f};

  #pragma unroll
  for (int ks = 0; ks < 4; ++ks) {
    const int kc = ks * 4 + quad;
    const int abase = kc * 128 + wi + (l15 ^ kc);
    const int bbase = kc * 128 + wj + (l15 ^ kc);
    bf16x8 af[4], bfr[4];
    #pragma unroll
    for (int t = 0; t < 4; ++t) {
      af[t] = Asv[abase + t * 16];
      bfr[t] = Bsv[bbase + t * 16];
    }
    #pragma unroll
    for (int ti = 0; ti < 4; ++ti)
      #pragma unroll
      for (int tj = 0; tj < 4; ++tj)
        acc[ti][tj] = __builtin_amdgcn_mfma_f32_16x16x32_bf16(
            af[ti], bfr[tj], acc[ti][tj], 0, 0, 0);
  }

  // epilogue: C[row][col], row=wi+ti*16+quad*4+r, col=wj+tj*16+l15 (raw dots)
  float p_s[16], n_s[16], cp[4], cn[4], cmax[4];
  #pragma unroll
  for (int i = 0; i < 16; ++i) { p_s[i] = 0.f; n_s[i] = 0.f; }
  #pragma unroll
  for (int tj = 0; tj < 4; ++tj) { cp[tj] = 0.f; cn[tj] = 0.f; cmax[tj] = -1e30f; }

  #pragma unroll
  for (int ti = 0; ti < 4; ++ti)
    #pragma unroll
    for (int r = 0; r < 4; ++r) {
      int si = ti * 4 + r;
      float l0 = acc[ti][0][r], l1 = acc[ti][1][r];
      float l2 = acc[ti][2][r], l3 = acc[ti][3][r];
      cmax[0] = fmaxf(cmax[0], l0);
      cmax[1] = fmaxf(cmax[1], l1);
      cmax[2] = fmaxf(cmax[2], l2);
      cmax[3] = fmaxf(cmax[3], l3);
      float tm = fmaxf(fmaxf(l0, l1), fmaxf(l2, l3));
      if (tm > srow[si] - 6.3f) {  // row-side slow path (rare: ~diag only)
        int lrow = wi + ti * 16 + quad * 4 + r;
        uint4 la = rLbS[lrow];
        int ra = rRsS[lrow];
        float p = p_s[si], n = n_s[si];
        float lv[4] = {l0, l1, l2, l3};
        #pragma unroll
        for (int tj = 0; tj < 4; ++tj) {
          float e = __expf((lv[tj] - srow[si]) * invT);
          int lcol = wj + tj * 16 + l15;
          uint4 lb = cLbS[lcol];
          int inter = __popc(la.x & lb.x) + __popc(la.y & lb.y) +
                      __popc(la.z & lb.z) + __popc(la.w & lb.w);
          if (3 * inter > ra + cRsS[lcol]) p += e; else n += e;  // sim>=0.5 exact
        }
        p_s[si] = p;
        n_s[si] = n;
      }
    }

  // col-side (transpose contribution) — off-diagonal tiles only
  if (!diag) {
    #pragma unroll
    for (int tj = 0; tj < 4; ++tj) {
      if (cmax[tj] > scol[tj] - 6.3f) {  // rare
        int lcol = wj + tj * 16 + l15;
        uint4 lb = cLbS[lcol];
        int rb = cRsS[lcol];
        float p = cp[tj], n = cn[tj];
        #pragma unroll
        for (int ti = 0; ti < 4; ++ti)
          #pragma unroll
          for (int r = 0; r < 4; ++r) {
            float e = __expf((acc[ti][tj][r] - scol[tj]) * invT);
            int lrow = wi + ti * 16 + quad * 4 + r;
            uint4 la = rLbS[lrow];
            int inter = __popc(la.x & lb.x) + __popc(la.y & lb.y) +
                        __popc(la.z & lb.z) + __popc(la.w & lb.w);
            if (3 * inter > rRsS[lrow] + rb) p += e; else n += e;
          }
        cp[tj] = p;
        cn[tj] = n;
      }
    }
  }

  // row-side: sum across the 16 lanes (same quad) sharing each row
  #pragma unroll
  for (int si = 0; si < 16; ++si) {
    float p = p_s[si], n = n_s[si];
    #pragma unroll
    for (int o = 8; o >= 1; o >>= 1) {
      p += __shfl_xor(p, o);
      n += __shfl_xor(n, o);
    }
    p_s[si] = p;
    n_s[si] = n;
  }
  // col-side: sum across the 4 quads sharing each column
  #pragma unroll
  for (int tj = 0; tj < 4; ++tj) {
    float p = cp[tj], n = cn[tj];
    p += __shfl_xor(p, 16); n += __shfl_xor(n, 16);
    p += __shfl_xor(p, 32); n += __shfl_xor(n, 32);
    cp[tj] = p;
    cn[tj] = n;
  }

  // cross-wave merges via LDS (As dead; mrow 1 KB, mcol next 1 KB)
  __syncthreads();
  float* mrow = (float*)As;
  float* mcol = ((float*)As) + 256;
  if (wj == 64 && l15 == 0) {  // waves 2,3: row partials
    #pragma unroll
    for (int ti = 0; ti < 4; ++ti)
      #pragma unroll
      for (int r = 0; r < 4; ++r) {
        int row = wi + ti * 16 + quad * 4 + r;
        int si = ti * 4 + r;
        mrow[row * 2 + 0] = p_s[si];
        mrow[row * 2 + 1] = n_s[si];
      }
  }
  if (!diag && wi == 64 && quad == 0) {  // waves 1,3: col partials
    #pragma unroll
    for (int tj = 0; tj < 4; ++tj) {
      int col = wj + tj * 16 + l15;
      mcol[col * 2 + 0] = cp[tj];
      mcol[col * 2 + 1] = cn[tj];
    }
  }
  __syncthreads();
  if (wj == 0 && l15 == 0) {  // waves 0,1: row final -> part[by][...]
    #pragma unroll
    for (int ti = 0; ti < 4; ++ti)
      #pragma unroll
      for (int r = 0; r < 4; ++r) {
        int row = wi + ti * 16 + quad * 4 + r;
        int si = ti * 4 + r;
        float p = p_s[si] + mrow[row * 2 + 0];
        float n = n_s[si] + mrow[row * 2 + 1];
        part[(size_t)by * B_ROWS + rowBase + row] = make_float2(p, n);
      }
  }
  if (!diag && wi == 0 && quad == 0) {  // waves 0,2: col final -> part[bx][...]
    #pragma unroll
    for (int tj = 0; tj < 4; ++tj) {
      int col = wj + tj * 16 + l15;
      float p = cp[tj] + mcol[col * 2 + 0];
      float n = cn[tj] + mcol[col * 2 + 1];
      part[(size_t)bx * B_ROWS + colBase + col] = make_float2(p, n);
    }
  }
}

// 16 blocks x 256: one row per thread, 32 slot loads, per-row loss, wave
// reduction, one atomic per wave.
__global__ void merge_kernel(const float2* __restrict__ part,
                             const int* __restrict__ rsv,
                             float* __restrict__ accum) {
  int row = blockIdx.x * 256 + threadIdx.x;
  float p = 0.f, n = 0.f;
  #pragma unroll
  for (int c = 0; c < NCT; ++c) {
    float2 v = part[(size_t)c * B_ROWS + row];
    p += v.x;
    n += v.y;
  }
  float per = 0.f, cnt = 0.f;
  if (rsv[row] > 0) {  // exact: has_pos <=> row_sum > 0
    per = -logf(p / (p + n));
    cnt = 1.f;
  }
  #pragma unroll
  for (int o = 32; o >= 1; o >>= 1) {
    per += __shfl_xor(per, o);
    cnt += __shfl_xor(cnt, o);
  }
  if ((threadIdx.x & 63) == 0) {
    atomicAdd(accum + 0, per);
    atomicAdd(accum + 1, cnt);
  }
}

__global__ void fin_kernel(const float* __restrict__ accum,
                           float* __restrict__ out) {
  out[0] = accum[0] / fmaxf(accum[1], 1.0f);
}

extern "C" void kernel_launch(void* const* d_in, const int* in_sizes, int n_in,
                              void* d_out, int out_size, void* d_ws, size_t ws_size,
                              hipStream_t stream) {
  const float* feat = (const float*)d_in[0];
  const float* labels = (const float*)d_in[1];
  float* out = (float*)d_out;
  char* ws = (char*)d_ws;
  // workspace (~2.1 MB):
  uint4* cf = (uint4*)(ws + 0);               // 1 MB swizzled bf16 view0
  uint4* Lbm = (uint4*)(ws + 1048576);        // 64 KB label masks
  int* rsv = (int*)(ws + 1114112);            // 16 KB row sums
  float* seedRaw = (float*)(ws + 1130496);    // 16 KB diag seeds
  float2* part = (float2*)(ws + 1146880);     // 1 MB partials (32 x 4096)
  float* accum = (float*)(ws + 1146880 + 1048576);  // 8 B

  hipLaunchKernelGGL(pack_kernel, dim3(256), dim3(256), 0, stream, feat, cf);
  hipLaunchKernelGGL(seedlabel_kernel, dim3(1024), dim3(256), 0, stream,
                     feat, labels, Lbm, rsv, seedRaw, accum);
  hipLaunchKernelGGL(main_kernel, dim3(NTRI), dim3(256), 0, stream,
                     cf, Lbm, rsv, seedRaw, part);
  hipLaunchKernelGGL(merge_kernel, dim3(B_ROWS / 256), dim3(256), 0, stream,
                     part, rsv, accum);
  hipLaunchKernelGGL(fin_kernel, dim3(1), dim3(1), 0, stream, accum, out);
}

// Round 9
// 82.671 us; speedup vs baseline: 1.2764x; 1.0077x over previous
//
#include <hip/hip_runtime.h>
#include <math.h>

#define B_ROWS 4096
#define LBL 100
#define NCT 32     // 32x32 tile grid, upper triangle only
#define NTRI 528   // 32*33/2 blocks

typedef __attribute__((ext_vector_type(8))) short bf16x8;
typedef __attribute__((ext_vector_type(4))) float f32x4;

__device__ __forceinline__ unsigned f2bf(float x) {
  union { float f; unsigned u; } a; a.f = x;
  unsigned r = a.u + 0x7fffu + ((a.u >> 16) & 1u);  // RNE
  return r >> 16;
}
__device__ __forceinline__ float bf2f(unsigned h) {
  return __uint_as_float(h << 16);
}

// Fused prep: one wave per row. Writes cf (bf16 view0, XOR-swizzled chunks:
// chunk(r,kc) of tile t at cf[t*2048 + kc*128 + ((r&127)^kc)]), 128-bit label
// masks, row sums, seedRaw = sum(bf16(f)^2) - 0.15 (lower bound on the raw
// diag MFMA dot; single source -> bit-identical for all consumers).
// Block 0 zeroes accum + counter.
__global__ void prep_kernel(const float* __restrict__ feat,
                            const float* __restrict__ labels,
                            uint4* __restrict__ cf,
                            uint4* __restrict__ Lb,
                            int* __restrict__ rsv,
                            float* __restrict__ seedRaw,
                            float* __restrict__ accum,
                            unsigned* __restrict__ counter) {
  if (blockIdx.x == 0 && threadIdx.x < 2) accum[threadIdx.x] = 0.0f;
  if (blockIdx.x == 0 && threadIdx.x == 2) *counter = 0u;
  int w = blockIdx.x * 4 + (threadIdx.x >> 6);
  int lane = threadIdx.x & 63;
  float2 f = ((const float2*)(feat + (size_t)w * 256))[lane];  // view0 row
  unsigned u0 = f2bf(f.x), u1 = f2bf(f.y);
  unsigned myu = u0 | (u1 << 16);
  float b0 = bf2f(u0), b1 = bf2f(u1);
  float s = b0 * b0 + b1 * b1;
  #pragma unroll
  for (int o = 32; o >= 1; o >>= 1) s += __shfl_xor(s, o);
  float x0 = labels[(size_t)w * LBL + lane];
  float x1 = (lane < LBL - 64) ? labels[(size_t)w * LBL + 64 + lane] : 0.0f;
  unsigned long long m0 = __ballot(x0 != 0.0f);
  unsigned long long m1 = __ballot(x1 != 0.0f);
  // pack: lane kc<16 gathers its chunk's 4 dwords from lanes kc*4+j
  int kc = lane & 15;
  unsigned q0 = __shfl(myu, kc * 4 + 0);
  unsigned q1 = __shfl(myu, kc * 4 + 1);
  unsigned q2 = __shfl(myu, kc * 4 + 2);
  unsigned q3 = __shfl(myu, kc * 4 + 3);
  if (lane < 16)
    cf[(size_t)(w >> 7) * 2048 + kc * 128 + ((w & 127) ^ kc)] =
        make_uint4(q0, q1, q2, q3);
  if (lane == 0) {
    Lb[w] = make_uint4((unsigned)m0, (unsigned)(m0 >> 32),
                       (unsigned)m1, (unsigned)(m1 >> 32));
    rsv[w] = __popcll(m0) + __popcll(m1);
    seedRaw[w] = s - 0.15f;  // 0.15 raw = 2.1 logit slack >> 1e-3 reassoc err
  }
}

// One upper-triangle 128x128 tile per block — ZERO LDS, ZERO barriers.
// MFMA A/B fragments load directly from the pre-swizzled cf (per quad: 16
// lanes -> one 256B segment, perfectly coalesced), double-buffered in regs
// across the 4 K-steps. Raw dots; *invT in epilogue. logits_max cancels in
// -log(p/(p+n)); terms below ref-6.3 raw (=90 logits under the diag logit)
// underflow to 0 in the reference's fp32 sums too. Cross-wave merge avoided:
// each wave-half owns slot part2[c*2+h] (c = other tile index, h = half);
// every (row, slot) written exactly once across the triangle.
__launch_bounds__(256)
__global__ void main_kernel(const uint4* __restrict__ cf,
                            const uint4* __restrict__ Lb,
                            const int* __restrict__ rsv,
                            const float* __restrict__ seedRaw,
                            float2* __restrict__ part2) {
  // triangular decode: bid -> (bx, by), bx <= by
  int bid = blockIdx.x;
  int bx = 0, off = 0;
  while (bid >= off + (NCT - bx)) { off += NCT - bx; ++bx; }
  int by = bx + (bid - off);
  const bool diag = (bx == by);

  const int tid = threadIdx.x;
  const int lane = tid & 63;
  const int l15 = lane & 15;
  const int quad = lane >> 4;
  const int wave = tid >> 6;
  const int wi = (wave & 1) * 64;   // wave row offset in 128
  const int wj = (wave >> 1) * 64;  // wave col offset in 128
  const int rowBase = bx * 128;
  const int colBase = by * 128;
  const float invT = 1.0f / 0.07f;

  const uint4* Ab = cf + (size_t)bx * 2048;
  const uint4* Bb = cf + (size_t)by * 2048;

  f32x4 acc[4][4];
  #pragma unroll
  for (int ti = 0; ti < 4; ++ti)
    #pragma unroll
    for (int tj = 0; tj < 4; ++tj)
      acc[ti][tj] = (f32x4){0.f, 0.f, 0.f, 0.f};

  // K loop, register double-buffered fragment loads straight from global
  bf16x8 af[4], bfr[4], af2[4], bfr2[4];
  {
    const int kc = quad;
    #pragma unroll
    for (int t = 0; t < 4; ++t) {
      af[t]  = *(const bf16x8*)&Ab[kc * 128 + ((wi + t * 16 + l15) ^ kc)];
      bfr[t] = *(const bf16x8*)&Bb[kc * 128 + ((wj + t * 16 + l15) ^ kc)];
    }
  }
  #pragma unroll
  for (int ks = 0; ks < 4; ++ks) {
    if (ks < 3) {
      const int kc = (ks + 1) * 4 + quad;
      #pragma unroll
      for (int t = 0; t < 4; ++t) {
        af2[t]  = *(const bf16x8*)&Ab[kc * 128 + ((wi + t * 16 + l15) ^ kc)];
        bfr2[t] = *(const bf16x8*)&Bb[kc * 128 + ((wj + t * 16 + l15) ^ kc)];
      }
    }
    #pragma unroll
    for (int ti = 0; ti < 4; ++ti)
      #pragma unroll
      for (int tj = 0; tj < 4; ++tj)
        acc[ti][tj] = __builtin_amdgcn_mfma_f32_16x16x32_bf16(
            af[ti], bfr[tj], acc[ti][tj], 0, 0, 0);
    if (ks < 3) {
      #pragma unroll
      for (int t = 0; t < 4; ++t) { af[t] = af2[t]; bfr[t] = bfr2[t]; }
    }
  }

  // per-wave metadata (coalesced; one latency, L2-hot)
  uint4 clb[4];
  int crs[4];
  float scol[4], srow[16];
  #pragma unroll
  for (int tj = 0; tj < 4; ++tj) {
    int gcol = colBase + wj + tj * 16 + l15;
    clb[tj] = Lb[gcol];
    crs[tj] = rsv[gcol];
    scol[tj] = seedRaw[gcol];
  }
  #pragma unroll
  for (int ti = 0; ti < 4; ++ti) {
    float4 s4 = *(const float4*)&seedRaw[rowBase + wi + ti * 16 + quad * 4];
    srow[ti * 4 + 0] = s4.x; srow[ti * 4 + 1] = s4.y;
    srow[ti * 4 + 2] = s4.z; srow[ti * 4 + 3] = s4.w;
  }

  // epilogue: C[row][col], row=wi+ti*16+quad*4+r, col=wj+tj*16+l15 (raw dots)
  float p_s[16], n_s[16], cp[4], cn[4], cmax[4];
  #pragma unroll
  for (int i = 0; i < 16; ++i) { p_s[i] = 0.f; n_s[i] = 0.f; }
  #pragma unroll
  for (int tj = 0; tj < 4; ++tj) { cp[tj] = 0.f; cn[tj] = 0.f; cmax[tj] = -1e30f; }

  #pragma unroll
  for (int ti = 0; ti < 4; ++ti)
    #pragma unroll
    for (int r = 0; r < 4; ++r) {
      int si = ti * 4 + r;
      float l0 = acc[ti][0][r], l1 = acc[ti][1][r];
      float l2 = acc[ti][2][r], l3 = acc[ti][3][r];
      cmax[0] = fmaxf(cmax[0], l0);
      cmax[1] = fmaxf(cmax[1], l1);
      cmax[2] = fmaxf(cmax[2], l2);
      cmax[3] = fmaxf(cmax[3], l3);
      float tm = fmaxf(fmaxf(l0, l1), fmaxf(l2, l3));
      if (tm > srow[si] - 6.3f) {  // row-side slow path (~diag tiles only)
        int grow = rowBase + wi + ti * 16 + quad * 4 + r;
        uint4 la = Lb[grow];     // scattered but rare + L2-hot
        int ra = rsv[grow];
        float p = p_s[si], n = n_s[si];
        float lv[4] = {l0, l1, l2, l3};
        #pragma unroll
        for (int tj = 0; tj < 4; ++tj) {
          float e = __expf((lv[tj] - srow[si]) * invT);
          int inter = __popc(la.x & clb[tj].x) + __popc(la.y & clb[tj].y) +
                      __popc(la.z & clb[tj].z) + __popc(la.w & clb[tj].w);
          if (3 * inter > ra + crs[tj]) p += e; else n += e;  // sim>=0.5 exact
        }
        p_s[si] = p;
        n_s[si] = n;
      }
    }

  // col-side (transpose contribution) — off-diagonal tiles only, ~never fires
  if (!diag) {
    #pragma unroll
    for (int tj = 0; tj < 4; ++tj) {
      if (cmax[tj] > scol[tj] - 6.3f) {
        float p = cp[tj], n = cn[tj];
        #pragma unroll
        for (int ti = 0; ti < 4; ++ti)
          #pragma unroll
          for (int r = 0; r < 4; ++r) {
            float e = __expf((acc[ti][tj][r] - scol[tj]) * invT);
            int grow = rowBase + wi + ti * 16 + quad * 4 + r;
            uint4 la = Lb[grow];
            int inter = __popc(la.x & clb[tj].x) + __popc(la.y & clb[tj].y) +
                        __popc(la.z & clb[tj].z) + __popc(la.w & clb[tj].w);
            if (3 * inter > rsv[grow] + crs[tj]) p += e; else n += e;
          }
        cp[tj] = p;
        cn[tj] = n;
      }
    }
  }

  // row-side: sum across the 16 lanes (same quad) sharing each row, then the
  // wave writes ITS OWN slot h=(wj>>6) — no cross-wave merge, no barrier.
  #pragma unroll
  for (int si = 0; si < 16; ++si) {
    float p = p_s[si], n = n_s[si];
    #pragma unroll
    for (int o = 8; o >= 1; o >>= 1) {
      p += __shfl_xor(p, o);
      n += __shfl_xor(n, o);
    }
    p_s[si] = p;
    n_s[si] = n;
  }
  if (l15 == 0) {
    int sc = by * 2 + (wj >> 6);
    #pragma unroll
    for (int ti = 0; ti < 4; ++ti)
      #pragma unroll
      for (int r = 0; r < 4; ++r) {
        int row = rowBase + wi + ti * 16 + quad * 4 + r;
        part2[(size_t)sc * B_ROWS + row] =
            make_float2(p_s[ti * 4 + r], n_s[ti * 4 + r]);
      }
  }
  // col-side: sum across the 4 quads sharing each column; slot h=(wi>>6)
  #pragma unroll
  for (int tj = 0; tj < 4; ++tj) {
    float p = cp[tj], n = cn[tj];
    p += __shfl_xor(p, 16); n += __shfl_xor(n, 16);
    p += __shfl_xor(p, 32); n += __shfl_xor(n, 32);
    cp[tj] = p;
    cn[tj] = n;
  }
  if (!diag && quad == 0) {
    int sc = bx * 2 + (wi >> 6);
    #pragma unroll
    for (int tj = 0; tj < 4; ++tj) {
      int col = colBase + wj + tj * 16 + l15;
      part2[(size_t)sc * B_ROWS + col] = make_float2(cp[tj], cn[tj]);
    }
  }
}

// 16 blocks x 256: one row per thread, 64 coalesced slot loads, per-row loss,
// wave reduction, one atomic per wave; last block (counter) finalizes out.
__global__ void mergefin_kernel(const float2* __restrict__ part2,
                                const int* __restrict__ rsv,
                                float* __restrict__ accum,
                                unsigned* __restrict__ counter,
                                float* __restrict__ out) {
  int row = blockIdx.x * 256 + threadIdx.x;
  float p = 0.f, n = 0.f;
  #pragma unroll
  for (int c = 0; c < 2 * NCT; ++c) {
    float2 v = part2[(size_t)c * B_ROWS + row];
    p += v.x;
    n += v.y;
  }
  float per = 0.f, cnt = 0.f;
  if (rsv[row] > 0) {  // exact: has_pos <=> row_sum > 0
    per = -logf(p / (p + n));
    cnt = 1.f;
  }
  #pragma unroll
  for (int o = 32; o >= 1; o >>= 1) {
    per += __shfl_xor(per, o);
    cnt += __shfl_xor(cnt, o);
  }
  if ((threadIdx.x & 63) == 0) {
    atomicAdd(accum + 0, per);
    atomicAdd(accum + 1, cnt);
  }
  __syncthreads();               // all 4 waves' atomics issued+done
  __threadfence();               // order accum adds before counter add
  __shared__ unsigned done;
  if (threadIdx.x == 0) done = atomicAdd(counter, 1u);
  __syncthreads();
  if (done == 15 && threadIdx.x == 0) {  // last block finalizes
    __threadfence();
    float P = atomicAdd(accum + 0, 0.0f);  // device-scope coherent read
    float C = atomicAdd(accum + 1, 0.0f);
    out[0] = P / fmaxf(C, 1.0f);
  }
}

extern "C" void kernel_launch(void* const* d_in, const int* in_sizes, int n_in,
                              void* d_out, int out_size, void* d_ws, size_t ws_size,
                              hipStream_t stream) {
  const float* feat = (const float*)d_in[0];
  const float* labels = (const float*)d_in[1];
  float* out = (float*)d_out;
  char* ws = (char*)d_ws;
  // workspace (~3.2 MB):
  uint4* cf = (uint4*)(ws + 0);               // 1 MB swizzled bf16 view0
  uint4* Lbm = (uint4*)(ws + 1048576);        // 64 KB label masks
  int* rsv = (int*)(ws + 1114112);            // 16 KB row sums
  float* seedRaw = (float*)(ws + 1130496);    // 16 KB diag seeds
  float2* part2 = (float2*)(ws + 1146880);    // 2 MB partials (64 x 4096)
  float* accum = (float*)(ws + 1146880 + 2097152);      // 8 B
  unsigned* counter = (unsigned*)(ws + 1146880 + 2097152 + 8);  // 4 B

  hipLaunchKernelGGL(prep_kernel, dim3(1024), dim3(256), 0, stream,
                     feat, labels, cf, Lbm, rsv, seedRaw, accum, counter);
  hipLaunchKernelGGL(main_kernel, dim3(NTRI), dim3(256), 0, stream,
                     cf, Lbm, rsv, seedRaw, part2);
  hipLaunchKernelGGL(mergefin_kernel, dim3(B_ROWS / 256), dim3(256), 0, stream,
                     part2, rsv, accum, counter, out);
}